// Round 2
// 186.505 us; speedup vs baseline: 1.0107x; 1.0107x over previous
//
#include <hip/hip_runtime.h>
#include <math.h>

// Problem constants
#define B_  64
#define T_  256
#define IN_ 512
#define HID_ 1024
#define OUT_ 256
#define NDOM 20

typedef __bf16 bf16_t;
typedef __bf16 bf16x8 __attribute__((ext_vector_type(8)));
typedef __bf16 bf16x4 __attribute__((ext_vector_type(4)));
typedef float  f32x4  __attribute__((ext_vector_type(4)));

// fp32 -> bf16 RNE, pure bit math (used by the weight pre-pass)
__device__ __forceinline__ unsigned f2bf_bits(float f) {
    unsigned u = __builtin_bit_cast(unsigned, f);
    return (u + 0x7FFFu + ((u >> 16) & 1u)) >> 16;
}
__device__ __forceinline__ unsigned pack_bf16x2(float x, float y) {
    return f2bf_bits(x) | (f2bf_bits(y) << 16);
}

// Async global->LDS, 16 B per lane. LDS dest = wave-uniform base + lane*16 (m104).
__device__ __forceinline__ void gl_lds16(const void* g, void* l) {
    __builtin_amdgcn_global_load_lds(
        (const __attribute__((address_space(1))) unsigned*)g,
        (__attribute__((address_space(3))) unsigned*)l,
        16, 0, 0);
}

// Branchless exact-gelu via Abramowitz-Stegun 7.1.26 erf (|err| <= 1.5e-7).
__device__ __forceinline__ float gelu_fast(float v) {
    const float t = v * 0.70710678118654752f;
    const float a = __builtin_fabsf(t);
    const float k = __builtin_amdgcn_rcpf(__builtin_fmaf(0.3275911f, a, 1.0f));
    float p = __builtin_fmaf(1.061405429f, k, -1.453152027f);
    p = __builtin_fmaf(p, k, 1.421413741f);
    p = __builtin_fmaf(p, k, -0.284496736f);
    p = __builtin_fmaf(p, k, 0.254829592f);
    p = p * k;
    const float e  = __expf(-a * a);
    const float er = __builtin_fmaf(-p, e, 1.0f);          // erf(|t|)
    const float erf_t = __builtin_copysignf(er, t);
    return 0.5f * v * (1.0f + erf_t);
}

// ---------------------------------------------------------------------------
// Pre-pass: per-domain W (K x N fp32) -> Wt (N x K bf16), bias fp32. (unchanged)
template<int K, int N>
__global__ __launch_bounds__(256) void cvt_transpose(
    const float* __restrict__ table, bf16_t* __restrict__ Wt, float* __restrict__ BiasOut)
{
    const int d  = blockIdx.z;
    const float* W = table + (size_t)d * ((size_t)K * N + N);
    const int n0 = blockIdx.x * 64;
    const int k0 = blockIdx.y * 64;
    const int tid = threadIdx.x;

    __shared__ float t[64][65];

    #pragma unroll
    for (int r = 0; r < 4; ++r) {
        const int kl = (tid >> 4) + r * 16;
        const int nl = (tid & 15) * 4;
        float4 v = *(const float4*)(W + (size_t)(k0 + kl) * N + n0 + nl);
        t[kl][nl + 0] = v.x; t[kl][nl + 1] = v.y;
        t[kl][nl + 2] = v.z; t[kl][nl + 3] = v.w;
    }
    __syncthreads();

    bf16_t* Wtd = Wt + (size_t)d * K * N;
    #pragma unroll
    for (int r = 0; r < 4; ++r) {
        const int nl = (tid >> 4) + r * 16;
        const int k4 = (tid & 15) * 4;
        uint2 p;
        p.x = pack_bf16x2(t[k4 + 0][nl], t[k4 + 1][nl]);
        p.y = pack_bf16x2(t[k4 + 2][nl], t[k4 + 3][nl]);
        *(uint2*)(Wtd + (size_t)(n0 + nl) * K + k0 + k4) = p;
    }

    if (blockIdx.y == 0 && tid < 64)
        BiasOut[(size_t)d * N + n0 + tid] = W[(size_t)K * N + n0 + tid];
}

// ---------------------------------------------------------------------------
// fc1: H[b] = gelu(X[b] (256x512 fp32, converted in-kernel) @ W1t[d]^T + b1), H bf16.
// 128x128 tile, BK=64. T3-min pipeline: double-buffered LDS, prefetch issued
// before compute, ONE barrier per K-step. A staged via reg-load fp32 -> cvt ->
// ds_write (same XOR-chunk layout as the gl_lds path); B via gl_lds16.
// NOTE: no array-of-LDS-pointer initializers (hipcc static-init addrspacecast bug);
// buffer select is runtime pointer arithmetic on the smem base.
#define CT_STRIDE 136   // epilogue row stride (bf16): 128 data + 8 pad
__global__ __launch_bounds__(256) void fc1_gemm(
    const float*  __restrict__ X,     // B x 256 x 512 fp32
    const bf16_t* __restrict__ W1t,   // D x 1024 x 512 [n][k]
    const float*  __restrict__ Bias,  // D x 1024
    const int*    __restrict__ hetero,
    bf16_t*       __restrict__ H)     // B x 256 x 1024
{
    const int id   = blockIdx.x;          // 1024 blocks
    const int g    = id & 127;            // stride-128 ids share X-tile -> same XCD
    const int nidx = id >> 7;
    const int b    = g >> 1;
    const int m0   = (g & 1) * 128;
    const int n0   = nidx * 128;
    const int d    = hetero[2 * b];
    const bf16_t* W    = W1t + (size_t)d * HID_ * IN_;
    const float*  bias = Bias + (size_t)d * HID_;
    const float*  A    = X + (size_t)(b * 256 + m0) * IN_;

    __shared__ __attribute__((aligned(16))) char smem[65536];   // 64 KB

    const int tid  = threadIdx.x;
    const int wave = tid >> 6;
    const int lane = tid & 63;
    const int l16  = lane & 15;
    const int quad = lane >> 4;
    const int wm   = (wave >> 1) * 64;
    const int wn   = (wave & 1) * 64;

    // A-staging map: thread handles 8 float4 (rows arow0+16r, float4-col acol4).
    const int arow0 = tid >> 4;   // 0..15
    const int acol4 = tid & 15;   // 0..15  (col = acol4*4 floats)

    f32x4 acc[4][4] = {};
    float4 pre[8];

    auto ldsA = [&](int nb) -> bf16_t* { return (bf16_t*)(smem + nb * 16384); };
    auto ldsB = [&](int nb) -> bf16_t* { return (bf16_t*)(smem + 32768 + nb * 16384); };

    auto loadA = [&](int kk) {
        #pragma unroll
        for (int r = 0; r < 8; ++r)
            pre[r] = *(const float4*)(A + (size_t)(arow0 + r * 16) * IN_ + kk + acol4 * 4);
    };
    // Store chunk p=acol4>>1 at swizzled chunk p^(row&7): byte-identical to the
    // gl_lds layout the read side expects. 16-lane group writes one full 128 B
    // row -> conflict-free.
    auto writeA = [&](bf16_t* dst) {
        #pragma unroll
        for (int r = 0; r < 8; ++r) {
            const int row = arow0 + r * 16;
            const int cs  = (acol4 >> 1) ^ (row & 7);
            bf16x4 w;
            w[0] = (bf16_t)pre[r].x; w[1] = (bf16_t)pre[r].y;
            w[2] = (bf16_t)pre[r].z; w[3] = (bf16_t)pre[r].w;
            *(bf16x4*)&dst[row * 64 + cs * 8 + (acol4 & 1) * 4] = w;
        }
    };
    auto stageB = [&](int kk, bf16_t* dst) {
        #pragma unroll
        for (int cc = 0; cc < 4; ++cc) {
            const int r0  = wave * 32 + cc * 8;
            const int row = r0 + (lane >> 3);
            const int cs  = (lane & 7) ^ (row & 7);
            gl_lds16(W + (size_t)(n0 + row) * IN_ + kk + cs * 8, dst + r0 * 64);
        }
    };
    auto compute = [&](const bf16_t* La, const bf16_t* Lb) {
        #pragma unroll
        for (int h = 0; h < 2; ++h) {
            bf16x8 af[4], bfg[4];
            #pragma unroll
            for (int i = 0; i < 4; ++i) {
                const int r = wm + i * 16 + l16;
                const int c = (h * 4 + quad) ^ (r & 7);
                af[i] = *(const bf16x8*)&La[r * 64 + c * 8];
            }
            #pragma unroll
            for (int j = 0; j < 4; ++j) {
                const int r = wn + j * 16 + l16;
                const int c = (h * 4 + quad) ^ (r & 7);
                bfg[j] = *(const bf16x8*)&Lb[r * 64 + c * 8];
            }
            #pragma unroll
            for (int i = 0; i < 4; ++i)
                #pragma unroll
                for (int j = 0; j < 4; ++j)   // swapped operands -> D^T
                    acc[i][j] = __builtin_amdgcn_mfma_f32_16x16x32_bf16(bfg[j], af[i], acc[i][j], 0, 0, 0);
        }
    };

    // Prologue
    loadA(0);
    stageB(0, ldsB(0));
    writeA(ldsA(0));
    __syncthreads();

    // Main loop: 8 K-steps, single barrier per step; prefetch (s+1) in flight
    // under compute(s). gl_lds counts in vmcnt only, so compute's ds_reads
    // don't wait on it; the end-of-step barrier drains everything.
    int buf = 0;
    for (int s = 0; s < 7; ++s) {
        loadA((s + 1) * 64);                 // A fp32 -> regs (in flight)
        stageB((s + 1) * 64, ldsB(buf ^ 1)); // B gl_lds (in flight)
        compute(ldsA(buf), ldsB(buf));
        writeA(ldsA(buf ^ 1));               // waits only on A loads
        __syncthreads();
        buf ^= 1;
    }
    compute(ldsA(buf), ldsB(buf));
    __syncthreads();                          // before Ct alias

    bf16_t* Ct = (bf16_t*)smem;               // epilogue [128][CT_STRIDE] (34816 B)

    // Epilogue: D^T: m = wm+i*16+l16, n = wn+j*16+quad*4 (+reg).
    #pragma unroll
    for (int i = 0; i < 4; ++i) {
        const int m = wm + i * 16 + l16;
        #pragma unroll
        for (int j = 0; j < 4; ++j) {
            const int nl = wn + j * 16 + quad * 4;
            const float4 b4 = *(const float4*)&bias[n0 + nl];
            bf16x4 w;
            w[0] = (bf16_t)gelu_fast(acc[i][j][0] + b4.x);
            w[1] = (bf16_t)gelu_fast(acc[i][j][1] + b4.y);
            w[2] = (bf16_t)gelu_fast(acc[i][j][2] + b4.z);
            w[3] = (bf16_t)gelu_fast(acc[i][j][3] + b4.w);
            *(bf16x4*)&Ct[m * CT_STRIDE + nl] = w;
        }
    }
    __syncthreads();

    // Coalesced H store: 128 rows x 256 B.
    #pragma unroll
    for (int it = 0; it < 8; ++it) {
        const int row = it * 16 + (tid >> 4);
        const int ch  = tid & 15;
        uint4 v = *(const uint4*)&Ct[row * CT_STRIDE + ch * 8];
        *(uint4*)&H[((size_t)(b * 256 + m0 + row)) * HID_ + n0 + ch * 8] = v;
    }
}

// ---------------------------------------------------------------------------
// fc2: out[b] = H[b] (256x1024 bf16) @ W2t[d]^T + b2, fp32 out.
// 64x64 tile, BK=64, double-buffered with single barrier per K-step.
__global__ __launch_bounds__(256) void fc2_gemm(
    const bf16_t* __restrict__ H,
    const bf16_t* __restrict__ W2t,   // D x 256 x 1024 [n][k]
    const float*  __restrict__ Bias,  // D x 256
    const int*    __restrict__ hetero,
    float*        __restrict__ Out)   // B x 256 x 256
{
    const int id   = blockIdx.x;          // 1024 blocks
    const int g    = id & 255;            // stride-256 ids share H-tile -> same XCD
    const int nidx = id >> 8;
    const int b    = g >> 2;
    const int m0   = (g & 3) * 64;
    const int n0   = nidx * 64;
    const int d    = hetero[2 * b];
    const bf16_t* W    = W2t + (size_t)d * OUT_ * HID_;
    const float*  bias = Bias + (size_t)d * OUT_;

    __shared__ __attribute__((aligned(16))) bf16_t LdsA[2][64 * 64];  // 2x8 KB
    __shared__ __attribute__((aligned(16))) bf16_t LdsB[2][64 * 64];  // 2x8 KB

    const int tid  = threadIdx.x;
    const int wave = tid >> 6;
    const int lane = tid & 63;
    const int l16  = lane & 15;
    const int quad = lane >> 4;
    const int wm   = (wave >> 1) * 32;
    const int wn   = (wave & 1) * 32;

    f32x4 acc[2][2] = {};

    auto stage = [&](int kk, int nb) {
        #pragma unroll
        for (int cc = 0; cc < 2; ++cc) {
            const int r0  = wave * 16 + cc * 8;
            const int row = r0 + (lane >> 3);
            const int cs  = (lane & 7) ^ (row & 7);
            gl_lds16(H + (size_t)(b * 256 + m0 + row) * HID_ + kk + cs * 8,
                     &LdsA[nb][r0 * 64]);
            gl_lds16(W + (size_t)(n0 + row) * HID_ + kk + cs * 8,
                     &LdsB[nb][r0 * 64]);
        }
    };
    auto compute = [&](int nb) {
        #pragma unroll
        for (int h = 0; h < 2; ++h) {
            bf16x8 af[2], bfg[2];
            #pragma unroll
            for (int i = 0; i < 2; ++i) {
                const int r = wm + i * 16 + l16;
                const int c = (h * 4 + quad) ^ (r & 7);
                af[i] = *(const bf16x8*)&LdsA[nb][r * 64 + c * 8];
            }
            #pragma unroll
            for (int j = 0; j < 2; ++j) {
                const int r = wn + j * 16 + l16;
                const int c = (h * 4 + quad) ^ (r & 7);
                bfg[j] = *(const bf16x8*)&LdsB[nb][r * 64 + c * 8];
            }
            #pragma unroll
            for (int i = 0; i < 2; ++i)
                #pragma unroll
                for (int j = 0; j < 2; ++j)   // swapped operands -> D^T
                    acc[i][j] = __builtin_amdgcn_mfma_f32_16x16x32_bf16(bfg[j], af[i], acc[i][j], 0, 0, 0);
        }
    };

    stage(0, 0);
    __syncthreads();
    int buf = 0;
    for (int s = 0; s < 15; ++s) {
        stage((s + 1) * 64, buf ^ 1);   // prefetch in flight under compute
        compute(buf);
        __syncthreads();
        buf ^= 1;
    }
    compute(buf);

    // Store: m = m0+wm+i*16+l16; n = n0+wn+j*16+quad*4 (+reg). 16 B dwordx4/lane.
    #pragma unroll
    for (int i = 0; i < 2; ++i) {
        const int m = m0 + wm + i * 16 + l16;
        #pragma unroll
        for (int j = 0; j < 2; ++j) {
            const int nl = wn + j * 16 + quad * 4;
            const float4 b4 = *(const float4*)&bias[n0 + nl];
            float4 o;
            o.x = acc[i][j][0] + b4.x;
            o.y = acc[i][j][1] + b4.y;
            o.z = acc[i][j][2] + b4.z;
            o.w = acc[i][j][3] + b4.w;
            *(float4*)&Out[(size_t)(b * 256 + m) * OUT_ + n0 + nl] = o;
        }
    }
}

extern "C" void kernel_launch(void* const* d_in, const int* in_sizes, int n_in,
                              void* d_out, int out_size, void* d_ws, size_t ws_size,
                              hipStream_t stream) {
    const float* x         = (const float*)d_in[0];
    const int*   hetero    = (const int*)d_in[1];
    const float* fc1_table = (const float*)d_in[2];
    const float* fc2_table = (const float*)d_in[3];
    float*       out       = (float*)d_out;

    // Workspace layout (65,114,112 B — same budget as prior rounds):
    char* ws = (char*)d_ws;
    bf16_t* W1t = (bf16_t*)(ws);                         // 20x1024x512 bf16 = 20,971,520
    bf16_t* W2t = (bf16_t*)(ws + 20971520);              // 20x256x1024 bf16 = 10,485,760
    float*  b1  = (float*)(ws + 31457280);               // 20x1024 fp32
    float*  b2  = (float*)(ws + 31539200);               // 20x256 fp32
    bf16_t* H   = (bf16_t*)(ws + 31559680);              // 64x256x1024 bf16 = 33,554,432

    cvt_transpose<IN_, HID_><<<dim3(HID_ / 64, IN_ / 64, NDOM), 256, 0, stream>>>(
        fc1_table, W1t, b1);
    cvt_transpose<HID_, OUT_><<<dim3(OUT_ / 64, HID_ / 64, NDOM), 256, 0, stream>>>(
        fc2_table, W2t, b2);

    fc1_gemm<<<dim3(1024), 256, 0, stream>>>(x, W1t, b1, hetero, H);
    fc2_gemm<<<dim3(1024), 256, 0, stream>>>(H, W2t, b2, hetero, out);
}

// Round 3
// 184.834 us; speedup vs baseline: 1.0199x; 1.0090x over previous
//
#include <hip/hip_runtime.h>
#include <math.h>

// Problem constants
#define B_  64
#define T_  256
#define IN_ 512
#define HID_ 1024
#define OUT_ 256
#define NDOM 20

typedef __bf16 bf16_t;
typedef __bf16 bf16x8 __attribute__((ext_vector_type(8)));
typedef __bf16 bf16x4 __attribute__((ext_vector_type(4)));
typedef float  f32x4  __attribute__((ext_vector_type(4)));

// fp32 -> bf16 RNE, pure bit math
__device__ __forceinline__ unsigned f2bf_bits(float f) {
    unsigned u = __builtin_bit_cast(unsigned, f);
    return (u + 0x7FFFu + ((u >> 16) & 1u)) >> 16;
}
__device__ __forceinline__ unsigned pack_bf16x2(float x, float y) {
    return f2bf_bits(x) | (f2bf_bits(y) << 16);
}

// Async global->LDS, 16 B per lane. LDS dest = wave-uniform base + lane*16 (m104).
__device__ __forceinline__ void gl_lds16(const void* g, void* l) {
    __builtin_amdgcn_global_load_lds(
        (const __attribute__((address_space(1))) unsigned*)g,
        (__attribute__((address_space(3))) unsigned*)l,
        16, 0, 0);
}

// Branchless exact-gelu via Abramowitz-Stegun 7.1.26 erf (|err| <= 1.5e-7).
__device__ __forceinline__ float gelu_fast(float v) {
    const float t = v * 0.70710678118654752f;
    const float a = __builtin_fabsf(t);
    const float k = __builtin_amdgcn_rcpf(__builtin_fmaf(0.3275911f, a, 1.0f));
    float p = __builtin_fmaf(1.061405429f, k, -1.453152027f);
    p = __builtin_fmaf(p, k, 1.421413741f);
    p = __builtin_fmaf(p, k, -0.284496736f);
    p = __builtin_fmaf(p, k, 0.254829592f);
    p = p * k;
    const float e  = __expf(-a * a);
    const float er = __builtin_fmaf(-p, e, 1.0f);          // erf(|t|)
    const float erf_t = __builtin_copysignf(er, t);
    return 0.5f * v * (1.0f + erf_t);
}

// ---------------------------------------------------------------------------
// X fp32 -> bf16 (dense copy-convert). 2,097,152 float4s; grid 8192 x 256.
__global__ __launch_bounds__(256) void cvt_x(
    const float* __restrict__ X, bf16_t* __restrict__ Xbf)
{
    const size_t idx = (size_t)blockIdx.x * 256 + threadIdx.x;
    float4 v = ((const float4*)X)[idx];
    uint2 p;
    p.x = pack_bf16x2(v.x, v.y);
    p.y = pack_bf16x2(v.z, v.w);
    ((uint2*)Xbf)[idx] = p;
}

// ---------------------------------------------------------------------------
// Pre-pass: per-domain W (K x N fp32) -> Wt (N x K bf16), bias fp32.
template<int K, int N>
__global__ __launch_bounds__(256) void cvt_transpose(
    const float* __restrict__ table, bf16_t* __restrict__ Wt, float* __restrict__ BiasOut)
{
    const int d  = blockIdx.z;
    const float* W = table + (size_t)d * ((size_t)K * N + N);
    const int n0 = blockIdx.x * 64;
    const int k0 = blockIdx.y * 64;
    const int tid = threadIdx.x;

    __shared__ float t[64][65];

    #pragma unroll
    for (int r = 0; r < 4; ++r) {
        const int kl = (tid >> 4) + r * 16;
        const int nl = (tid & 15) * 4;
        float4 v = *(const float4*)(W + (size_t)(k0 + kl) * N + n0 + nl);
        t[kl][nl + 0] = v.x; t[kl][nl + 1] = v.y;
        t[kl][nl + 2] = v.z; t[kl][nl + 3] = v.w;
    }
    __syncthreads();

    bf16_t* Wtd = Wt + (size_t)d * K * N;
    #pragma unroll
    for (int r = 0; r < 4; ++r) {
        const int nl = (tid >> 4) + r * 16;
        const int k4 = (tid & 15) * 4;
        uint2 p;
        p.x = pack_bf16x2(t[k4 + 0][nl], t[k4 + 1][nl]);
        p.y = pack_bf16x2(t[k4 + 2][nl], t[k4 + 3][nl]);
        *(uint2*)(Wtd + (size_t)(n0 + nl) * K + k0 + k4) = p;
    }

    if (blockIdx.y == 0 && tid < 64)
        BiasOut[(size_t)d * N + n0 + tid] = W[(size_t)K * N + n0 + tid];
}

// ---------------------------------------------------------------------------
// fc1: H[b] = gelu(Xbf[b] (256x512 bf16) @ W1t[d]^T + b1), H bf16.
// 128x128 tile, BK=32, double-buffered (32 KB GEMM LDS -> 4 blocks/CU) with
// single barrier per K-step: prefetch (s+1) via gl_lds in flight under
// compute(s); __syncthreads drains it only after compute hid the latency.
// Swizzle for 64 B rows (4 x 16B chunks): f(row) = (row>>1)&3 -> 2-way bank
// pattern on ds_read_b128 (free, m136).
#define CT_STRIDE 136   // epilogue row stride (bf16): 128 data + 8 pad
__global__ __launch_bounds__(256) void fc1_gemm(
    const bf16_t* __restrict__ Xbf,   // B x 256 x 512 bf16
    const bf16_t* __restrict__ W1t,   // D x 1024 x 512 [n][k]
    const float*  __restrict__ Bias,  // D x 1024
    const int*    __restrict__ hetero,
    bf16_t*       __restrict__ H)     // B x 256 x 1024
{
    const int id   = blockIdx.x;          // 1024 blocks
    const int g    = id & 127;            // stride-128 ids share X-tile -> same XCD
    const int nidx = id >> 7;
    const int b    = g >> 1;
    const int m0   = (g & 1) * 128;
    const int n0   = nidx * 128;
    const int d    = hetero[2 * b];
    const bf16_t* W    = W1t + (size_t)d * HID_ * IN_;
    const float*  bias = Bias + (size_t)d * HID_;
    const bf16_t* A    = Xbf + (size_t)(b * 256 + m0) * IN_;

    // 34816 B total: GEMM buffers in first 32 KB, epilogue Ct aliases whole thing.
    __shared__ __attribute__((aligned(16))) char smem[34816];

    const int tid  = threadIdx.x;
    const int wave = tid >> 6;
    const int lane = tid & 63;
    const int l16  = lane & 15;
    const int quad = lane >> 4;
    const int wm   = (wave >> 1) * 64;
    const int wn   = (wave & 1) * 64;

    f32x4 acc[4][4] = {};

    auto ldsA = [&](int nb) -> bf16_t* { return (bf16_t*)(smem + nb * 16384); };
    auto ldsB = [&](int nb) -> bf16_t* { return (bf16_t*)(smem + 8192 + nb * 16384); };

    // Stage 128 rows x 64 B (bf16, BK=32). Per gl_lds call: 16 rows, 4 chunks
    // each; global source pre-swizzled so LDS stays linear (m173).
    auto stageA = [&](int kk, bf16_t* dst) {
        #pragma unroll
        for (int cc = 0; cc < 2; ++cc) {
            const int r0  = wave * 32 + cc * 16;
            const int row = r0 + (lane >> 2);
            const int cs  = (lane & 3) ^ ((row >> 1) & 3);
            gl_lds16(A + (size_t)row * IN_ + kk + cs * 8, dst + r0 * 32);
        }
    };
    auto stageB = [&](int kk, bf16_t* dst) {
        #pragma unroll
        for (int cc = 0; cc < 2; ++cc) {
            const int r0  = wave * 32 + cc * 16;
            const int row = r0 + (lane >> 2);
            const int cs  = (lane & 3) ^ ((row >> 1) & 3);
            gl_lds16(W + (size_t)(n0 + row) * IN_ + kk + cs * 8, dst + r0 * 32);
        }
    };
    auto compute = [&](const bf16_t* La, const bf16_t* Lb) {
        bf16x8 af[4], bfg[4];
        #pragma unroll
        for (int i = 0; i < 4; ++i) {
            const int r = wm + i * 16 + l16;
            const int c = quad ^ ((r >> 1) & 3);
            af[i] = *(const bf16x8*)&La[r * 32 + c * 8];
        }
        #pragma unroll
        for (int j = 0; j < 4; ++j) {
            const int r = wn + j * 16 + l16;
            const int c = quad ^ ((r >> 1) & 3);
            bfg[j] = *(const bf16x8*)&Lb[r * 32 + c * 8];
        }
        #pragma unroll
        for (int i = 0; i < 4; ++i)
            #pragma unroll
            for (int j = 0; j < 4; ++j)   // swapped operands -> D^T
                acc[i][j] = __builtin_amdgcn_mfma_f32_16x16x32_bf16(bfg[j], af[i], acc[i][j], 0, 0, 0);
    };

    // Prologue
    stageA(0, ldsA(0));
    stageB(0, ldsB(0));
    __syncthreads();

    // 16 K-steps, single barrier each; prefetch in flight under compute.
    int buf = 0;
    for (int s = 0; s < 15; ++s) {
        stageA((s + 1) * 32, ldsA(buf ^ 1));
        stageB((s + 1) * 32, ldsB(buf ^ 1));
        compute(ldsA(buf), ldsB(buf));
        __syncthreads();
        buf ^= 1;
    }
    compute(ldsA(buf), ldsB(buf));
    __syncthreads();                          // before Ct alias

    bf16_t* Ct = (bf16_t*)smem;               // [128][CT_STRIDE] = 34816 B

    // Epilogue: D^T: m = wm+i*16+l16, n = wn+j*16+quad*4 (+reg).
    #pragma unroll
    for (int i = 0; i < 4; ++i) {
        const int m = wm + i * 16 + l16;
        #pragma unroll
        for (int j = 0; j < 4; ++j) {
            const int nl = wn + j * 16 + quad * 4;
            const float4 b4 = *(const float4*)&bias[n0 + nl];
            bf16x4 w;
            w[0] = (bf16_t)gelu_fast(acc[i][j][0] + b4.x);
            w[1] = (bf16_t)gelu_fast(acc[i][j][1] + b4.y);
            w[2] = (bf16_t)gelu_fast(acc[i][j][2] + b4.z);
            w[3] = (bf16_t)gelu_fast(acc[i][j][3] + b4.w);
            *(bf16x4*)&Ct[m * CT_STRIDE + nl] = w;
        }
    }
    __syncthreads();

    // Coalesced H store: 128 rows x 256 B.
    #pragma unroll
    for (int it = 0; it < 8; ++it) {
        const int row = it * 16 + (tid >> 4);
        const int ch  = tid & 15;
        uint4 v = *(const uint4*)&Ct[row * CT_STRIDE + ch * 8];
        *(uint4*)&H[((size_t)(b * 256 + m0 + row)) * HID_ + n0 + ch * 8] = v;
    }
}

// ---------------------------------------------------------------------------
// fc2: out[b] = H[b] (256x1024 bf16) @ W2t[d]^T + b2, fp32 out.
// 64(M)x128(N) tile, BK=64, double-buffered (48 KB), single barrier per step.
// 512 blocks (2/CU). 16 MFMA/step/wave. XOR-8 swizzle (128 B rows, proven).
__global__ __launch_bounds__(256) void fc2_gemm(
    const bf16_t* __restrict__ H,
    const bf16_t* __restrict__ W2t,   // D x 256 x 1024 [n][k]
    const float*  __restrict__ Bias,  // D x 256
    const int*    __restrict__ hetero,
    float*        __restrict__ Out)   // B x 256 x 256
{
    const int id   = blockIdx.x;          // 512 blocks
    const int g    = id & 255;            // stride-256 ids share H-tile -> same XCD
    const int nidx = id >> 8;             // 0..1
    const int b    = g >> 2;
    const int m0   = (g & 3) * 64;
    const int n0   = nidx * 128;
    const int d    = hetero[2 * b];
    const bf16_t* W    = W2t + (size_t)d * OUT_ * HID_;
    const float*  bias = Bias + (size_t)d * OUT_;
    const bf16_t* A    = H + (size_t)(b * 256 + m0) * HID_;

    __shared__ __attribute__((aligned(16))) char smem[49152];   // 48 KB

    const int tid  = threadIdx.x;
    const int wave = tid >> 6;
    const int lane = tid & 63;
    const int l16  = lane & 15;
    const int quad = lane >> 4;
    const int wm   = (wave >> 1) * 32;    // 2 m-halves of 32
    const int wn   = (wave & 1) * 64;     // 2 n-halves of 64

    f32x4 acc[2][4] = {};

    auto ldsA = [&](int nb) -> bf16_t* { return (bf16_t*)(smem + nb * 24576); };          // 64x64 = 8 KB
    auto ldsB = [&](int nb) -> bf16_t* { return (bf16_t*)(smem + 8192 + nb * 24576); };   // 128x64 = 16 KB

    auto stage = [&](int kk, int nb) {
        bf16_t* dA = ldsA(nb);
        bf16_t* dB = ldsB(nb);
        // A: 64 rows x 128 B; per wave 16 rows (2 calls of 8 rows).
        #pragma unroll
        for (int cc = 0; cc < 2; ++cc) {
            const int r0  = wave * 16 + cc * 8;
            const int row = r0 + (lane >> 3);
            const int cs  = (lane & 7) ^ (row & 7);
            gl_lds16(A + (size_t)row * HID_ + kk + cs * 8, dA + r0 * 64);
        }
        // B: 128 rows x 128 B; per wave 32 rows (4 calls of 8 rows).
        #pragma unroll
        for (int cc = 0; cc < 4; ++cc) {
            const int r0  = wave * 32 + cc * 8;
            const int row = r0 + (lane >> 3);
            const int cs  = (lane & 7) ^ (row & 7);
            gl_lds16(W + (size_t)(n0 + row) * HID_ + kk + cs * 8, dB + r0 * 64);
        }
    };
    auto compute = [&](int nb) {
        const bf16_t* La = ldsA(nb);
        const bf16_t* Lb = ldsB(nb);
        #pragma unroll
        for (int h = 0; h < 2; ++h) {
            bf16x8 af[2], bfg[4];
            #pragma unroll
            for (int i = 0; i < 2; ++i) {
                const int r = wm + i * 16 + l16;
                const int c = (h * 4 + quad) ^ (r & 7);
                af[i] = *(const bf16x8*)&La[r * 64 + c * 8];
            }
            #pragma unroll
            for (int j = 0; j < 4; ++j) {
                const int r = wn + j * 16 + l16;
                const int c = (h * 4 + quad) ^ (r & 7);
                bfg[j] = *(const bf16x8*)&Lb[r * 64 + c * 8];
            }
            #pragma unroll
            for (int i = 0; i < 2; ++i)
                #pragma unroll
                for (int j = 0; j < 4; ++j)   // swapped operands -> D^T
                    acc[i][j] = __builtin_amdgcn_mfma_f32_16x16x32_bf16(bfg[j], af[i], acc[i][j], 0, 0, 0);
        }
    };

    stage(0, 0);
    __syncthreads();
    int buf = 0;
    for (int s = 0; s < 15; ++s) {
        stage((s + 1) * 64, buf ^ 1);   // prefetch in flight under compute
        compute(buf);
        __syncthreads();
        buf ^= 1;
    }
    compute(buf);

    // Store: m = m0+wm+i*16+l16; n = n0+wn+j*16+quad*4 (+reg). 16 B dwordx4/lane.
    #pragma unroll
    for (int i = 0; i < 2; ++i) {
        const int m = m0 + wm + i * 16 + l16;
        #pragma unroll
        for (int j = 0; j < 4; ++j) {
            const int nl = wn + j * 16 + quad * 4;
            const float4 b4 = *(const float4*)&bias[n0 + nl];
            float4 o;
            o.x = acc[i][j][0] + b4.x;
            o.y = acc[i][j][1] + b4.y;
            o.z = acc[i][j][2] + b4.z;
            o.w = acc[i][j][3] + b4.w;
            *(float4*)&Out[(size_t)(b * 256 + m) * OUT_ + n0 + nl] = o;
        }
    }
}

extern "C" void kernel_launch(void* const* d_in, const int* in_sizes, int n_in,
                              void* d_out, int out_size, void* d_ws, size_t ws_size,
                              hipStream_t stream) {
    const float* x         = (const float*)d_in[0];
    const int*   hetero    = (const int*)d_in[1];
    const float* fc1_table = (const float*)d_in[2];
    const float* fc2_table = (const float*)d_in[3];
    float*       out       = (float*)d_out;

    // Workspace layout (65,114,112 B — same budget as prior rounds):
    char* ws = (char*)d_ws;
    bf16_t* W1t = (bf16_t*)(ws);                         // 20x1024x512 bf16 = 20,971,520
    bf16_t* W2t = (bf16_t*)(ws + 20971520);              // 20x256x1024 bf16 = 10,485,760
    float*  b1  = (float*)(ws + 31457280);               // 20x1024 fp32
    float*  b2  = (float*)(ws + 31539200);               // 20x256 fp32
    bf16_t* H   = (bf16_t*)(ws + 31559680);              // 64x256x1024 bf16 = 33,554,432

    // Xbf lives in d_out (16,777,216 B = exactly out_size*4): fc1 reads it,
    // fc2 overwrites d_out afterwards (stream-ordered).
    bf16_t* Xbf = (bf16_t*)d_out;

    cvt_x<<<dim3(8192), 256, 0, stream>>>(x, Xbf);
    cvt_transpose<IN_, HID_><<<dim3(HID_ / 64, IN_ / 64, NDOM), 256, 0, stream>>>(
        fc1_table, W1t, b1);
    cvt_transpose<HID_, OUT_><<<dim3(OUT_ / 64, HID_ / 64, NDOM), 256, 0, stream>>>(
        fc2_table, W2t, b2);

    fc1_gemm<<<dim3(1024), 256, 0, stream>>>(Xbf, W1t, b1, hetero, H);
    fc2_gemm<<<dim3(512), 256, 0, stream>>>(H, W2t, b2, hetero, out);
}

// Round 4
// 178.580 us; speedup vs baseline: 1.0556x; 1.0350x over previous
//
#include <hip/hip_runtime.h>
#include <math.h>

// Problem constants
#define B_  64
#define T_  256
#define IN_ 512
#define HID_ 1024
#define OUT_ 256
#define NDOM 20

typedef __bf16 bf16_t;
typedef __bf16 bf16x8 __attribute__((ext_vector_type(8)));
typedef __bf16 bf16x4 __attribute__((ext_vector_type(4)));
typedef float  f32x4  __attribute__((ext_vector_type(4)));

// fp32 -> bf16 RNE, pure bit math
__device__ __forceinline__ unsigned f2bf_bits(float f) {
    unsigned u = __builtin_bit_cast(unsigned, f);
    return (u + 0x7FFFu + ((u >> 16) & 1u)) >> 16;
}
__device__ __forceinline__ unsigned pack_bf16x2(float x, float y) {
    return f2bf_bits(x) | (f2bf_bits(y) << 16);
}

// Async global->LDS, 16 B per lane. LDS dest = wave-uniform base + lane*16 (m104).
__device__ __forceinline__ void gl_lds16(const void* g, void* l) {
    __builtin_amdgcn_global_load_lds(
        (const __attribute__((address_space(1))) unsigned*)g,
        (__attribute__((address_space(3))) unsigned*)l,
        16, 0, 0);
}

// Branchless exact-gelu via Abramowitz-Stegun 7.1.26 erf (|err| <= 1.5e-7).
__device__ __forceinline__ float gelu_fast(float v) {
    const float t = v * 0.70710678118654752f;
    const float a = __builtin_fabsf(t);
    const float k = __builtin_amdgcn_rcpf(__builtin_fmaf(0.3275911f, a, 1.0f));
    float p = __builtin_fmaf(1.061405429f, k, -1.453152027f);
    p = __builtin_fmaf(p, k, 1.421413741f);
    p = __builtin_fmaf(p, k, -0.284496736f);
    p = __builtin_fmaf(p, k, 0.254829592f);
    p = p * k;
    const float e  = __expf(-a * a);
    const float er = __builtin_fmaf(-p, e, 1.0f);          // erf(|t|)
    const float erf_t = __builtin_copysignf(er, t);
    return 0.5f * v * (1.0f + erf_t);
}

// ---------------------------------------------------------------------------
// Merged weight pre-pass: both tables in ONE launch (fewer kernel boundaries).
// Per 64x64 tile: W (K x N fp32) -> Wt (N x K bf16), bias fp32.
// Blocks [0,2560): fc1 (K=512,N=1024, 20 d x 8 k x 16 n).
// Blocks [2560,3840): fc2 (K=1024,N=256, 20 d x 16 k x 4 n).
__global__ __launch_bounds__(256) void cvt_weights(
    const float* __restrict__ T1, const float* __restrict__ T2,
    bf16_t* __restrict__ W1t, bf16_t* __restrict__ W2t,
    float* __restrict__ b1, float* __restrict__ b2)
{
    const int tid = threadIdx.x;
    int blk = blockIdx.x;
    const float* table; bf16_t* Wt; float* Bias;
    int K, N, d, n0, k0;
    if (blk < 2560) {
        d = blk >> 7; const int rem = blk & 127;
        k0 = (rem >> 4) * 64; n0 = (rem & 15) * 64;
        K = 512; N = 1024; table = T1; Wt = W1t; Bias = b1;
    } else {
        blk -= 2560;
        d = blk >> 6; const int rem = blk & 63;
        k0 = (rem >> 2) * 64; n0 = (rem & 3) * 64;
        K = 1024; N = 256; table = T2; Wt = W2t; Bias = b2;
    }
    const float* W = table + (size_t)d * ((size_t)K * N + N);

    __shared__ float t[64][65];

    #pragma unroll
    for (int r = 0; r < 4; ++r) {
        const int kl = (tid >> 4) + r * 16;
        const int nl = (tid & 15) * 4;
        float4 v = *(const float4*)(W + (size_t)(k0 + kl) * N + n0 + nl);
        t[kl][nl + 0] = v.x; t[kl][nl + 1] = v.y;
        t[kl][nl + 2] = v.z; t[kl][nl + 3] = v.w;
    }
    __syncthreads();

    bf16_t* Wtd = Wt + (size_t)d * K * N;
    #pragma unroll
    for (int r = 0; r < 4; ++r) {
        const int nl = (tid >> 4) + r * 16;
        const int k4 = (tid & 15) * 4;
        uint2 p;
        p.x = pack_bf16x2(t[k4 + 0][nl], t[k4 + 1][nl]);
        p.y = pack_bf16x2(t[k4 + 2][nl], t[k4 + 3][nl]);
        *(uint2*)(Wtd + (size_t)(n0 + nl) * K + k0 + k4) = p;
    }

    if (k0 == 0 && tid < 64)
        Bias[(size_t)d * N + n0 + tid] = W[(size_t)K * N + n0 + tid];
}

// ---------------------------------------------------------------------------
// fc1: H[b] = gelu(X[b] (256x512 fp32, converted in staging) @ W1t[d]^T + b1).
// 128x128 tile, BK=32, 32 KB GEMM LDS (4 blocks/CU), single barrier per step.
// A: fp32 reg-load -> cvt -> conflict-free ds_write (wave writes 16 rows x 64 B
// = 1 KB linear). B: gl_lds16. Swizzle invariant both paths: LDS chunk q of row
// r holds global chunk q ^ ((r>>1)&3); read side applies the same XOR.
#define CT_STRIDE 136   // epilogue row stride (bf16): 128 data + 8 pad
__global__ __launch_bounds__(256) void fc1_gemm(
    const float*  __restrict__ X,     // B x 256 x 512 fp32
    const bf16_t* __restrict__ W1t,   // D x 1024 x 512 [n][k]
    const float*  __restrict__ Bias,  // D x 1024
    const int*    __restrict__ hetero,
    bf16_t*       __restrict__ H)     // B x 256 x 1024
{
    const int id   = blockIdx.x;          // 1024 blocks
    const int g    = id & 127;            // stride-128 ids share X-tile -> same XCD
    const int nidx = id >> 7;
    const int b    = g >> 1;
    const int m0   = (g & 1) * 128;
    const int n0   = nidx * 128;
    const int d    = hetero[2 * b];
    const bf16_t* W    = W1t + (size_t)d * HID_ * IN_;
    const float*  bias = Bias + (size_t)d * HID_;
    const float*  A    = X + (size_t)(b * 256 + m0) * IN_;

    __shared__ __attribute__((aligned(16))) char smem[34816];

    const int tid  = threadIdx.x;
    const int wave = tid >> 6;
    const int lane = tid & 63;
    const int l16  = lane & 15;
    const int quad = lane >> 4;
    const int wm   = (wave >> 1) * 64;
    const int wn   = (wave & 1) * 64;

    // A-staging map: thread handles chunk p=tid&3 of rows (tid>>2) and (tid>>2)+64.
    const int ar = tid >> 2;   // 0..63
    const int ap = tid & 3;    // chunk (8 bf16 = 8 fp32 cols)

    f32x4 acc[4][4] = {};
    float4 pre[2][2];

    auto ldsA = [&](int nb) -> bf16_t* { return (bf16_t*)(smem + nb * 16384); };
    auto ldsB = [&](int nb) -> bf16_t* { return (bf16_t*)(smem + 8192 + nb * 16384); };

    auto loadA = [&](int kk) {
        #pragma unroll
        for (int r = 0; r < 2; ++r) {
            const float* src = A + (size_t)(ar + 64 * r) * IN_ + kk + ap * 8;
            pre[r][0] = *(const float4*)src;
            pre[r][1] = *(const float4*)(src + 4);
        }
    };
    auto writeA = [&](bf16_t* dst) {
        #pragma unroll
        for (int r = 0; r < 2; ++r) {
            const int row = ar + 64 * r;
            const int cs  = ap ^ ((row >> 1) & 3);
            bf16x8 w;
            w[0] = (bf16_t)pre[r][0].x; w[1] = (bf16_t)pre[r][0].y;
            w[2] = (bf16_t)pre[r][0].z; w[3] = (bf16_t)pre[r][0].w;
            w[4] = (bf16_t)pre[r][1].x; w[5] = (bf16_t)pre[r][1].y;
            w[6] = (bf16_t)pre[r][1].z; w[7] = (bf16_t)pre[r][1].w;
            *(bf16x8*)&dst[row * 32 + cs * 8] = w;
        }
    };
    auto stageB = [&](int kk, bf16_t* dst) {
        #pragma unroll
        for (int cc = 0; cc < 2; ++cc) {
            const int r0  = wave * 32 + cc * 16;
            const int row = r0 + (lane >> 2);
            const int cs  = (lane & 3) ^ ((row >> 1) & 3);
            gl_lds16(W + (size_t)(n0 + row) * IN_ + kk + cs * 8, dst + r0 * 32);
        }
    };
    auto compute = [&](const bf16_t* La, const bf16_t* Lb) {
        bf16x8 af[4], bfg[4];
        #pragma unroll
        for (int i = 0; i < 4; ++i) {
            const int r = wm + i * 16 + l16;
            const int c = quad ^ ((r >> 1) & 3);
            af[i] = *(const bf16x8*)&La[r * 32 + c * 8];
        }
        #pragma unroll
        for (int j = 0; j < 4; ++j) {
            const int r = wn + j * 16 + l16;
            const int c = quad ^ ((r >> 1) & 3);
            bfg[j] = *(const bf16x8*)&Lb[r * 32 + c * 8];
        }
        #pragma unroll
        for (int i = 0; i < 4; ++i)
            #pragma unroll
            for (int j = 0; j < 4; ++j)   // swapped operands -> D^T
                acc[i][j] = __builtin_amdgcn_mfma_f32_16x16x32_bf16(bfg[j], af[i], acc[i][j], 0, 0, 0);
    };

    // Prologue
    loadA(0);
    stageB(0, ldsB(0));
    writeA(ldsA(0));          // waits (vmcnt) only on the 4 A loads
    __syncthreads();

    // 16 K-steps, single barrier each; prefetch (s+1) in flight under compute(s).
    int buf = 0;
    for (int s = 0; s < 15; ++s) {
        loadA((s + 1) * 32);                 // A fp32 -> regs (oldest vm ops)
        stageB((s + 1) * 32, ldsB(buf ^ 1)); // B gl_lds (younger)
        compute(ldsA(buf), ldsB(buf));       // hides A/B latency
        writeA(ldsA(buf ^ 1));               // vmcnt(2): A data ready
        __syncthreads();
        buf ^= 1;
    }
    compute(ldsA(buf), ldsB(buf));
    __syncthreads();                          // before Ct alias

    bf16_t* Ct = (bf16_t*)smem;               // [128][CT_STRIDE] = 34816 B

    // Epilogue: D^T: m = wm+i*16+l16, n = wn+j*16+quad*4 (+reg).
    #pragma unroll
    for (int i = 0; i < 4; ++i) {
        const int m = wm + i * 16 + l16;
        #pragma unroll
        for (int j = 0; j < 4; ++j) {
            const int nl = wn + j * 16 + quad * 4;
            const float4 b4 = *(const float4*)&bias[n0 + nl];
            bf16x4 w;
            w[0] = (bf16_t)gelu_fast(acc[i][j][0] + b4.x);
            w[1] = (bf16_t)gelu_fast(acc[i][j][1] + b4.y);
            w[2] = (bf16_t)gelu_fast(acc[i][j][2] + b4.z);
            w[3] = (bf16_t)gelu_fast(acc[i][j][3] + b4.w);
            *(bf16x4*)&Ct[m * CT_STRIDE + nl] = w;
        }
    }
    __syncthreads();

    // Coalesced H store: 128 rows x 256 B.
    #pragma unroll
    for (int it = 0; it < 8; ++it) {
        const int row = it * 16 + (tid >> 4);
        const int ch  = tid & 15;
        uint4 v = *(const uint4*)&Ct[row * CT_STRIDE + ch * 8];
        *(uint4*)&H[((size_t)(b * 256 + m0 + row)) * HID_ + n0 + ch * 8] = v;
    }
}

// ---------------------------------------------------------------------------
// fc2: out[b] = H[b] (256x1024 bf16) @ W2t[d]^T + b2, fp32 out.
// 64(M)x128(N) tile, BK=64, double-buffered (48 KB), single barrier per step.
__global__ __launch_bounds__(256) void fc2_gemm(
    const bf16_t* __restrict__ H,
    const bf16_t* __restrict__ W2t,   // D x 256 x 1024 [n][k]
    const float*  __restrict__ Bias,  // D x 256
    const int*    __restrict__ hetero,
    float*        __restrict__ Out)   // B x 256 x 256
{
    const int id   = blockIdx.x;          // 512 blocks
    const int g    = id & 255;            // stride-256 ids share H-tile -> same XCD
    const int nidx = id >> 8;             // 0..1
    const int b    = g >> 2;
    const int m0   = (g & 3) * 64;
    const int n0   = nidx * 128;
    const int d    = hetero[2 * b];
    const bf16_t* W    = W2t + (size_t)d * OUT_ * HID_;
    const float*  bias = Bias + (size_t)d * OUT_;
    const bf16_t* A    = H + (size_t)(b * 256 + m0) * HID_;

    __shared__ __attribute__((aligned(16))) char smem[49152];   // 48 KB

    const int tid  = threadIdx.x;
    const int wave = tid >> 6;
    const int lane = tid & 63;
    const int l16  = lane & 15;
    const int quad = lane >> 4;
    const int wm   = (wave >> 1) * 32;
    const int wn   = (wave & 1) * 64;

    f32x4 acc[2][4] = {};

    auto ldsA = [&](int nb) -> bf16_t* { return (bf16_t*)(smem + nb * 24576); };
    auto ldsB = [&](int nb) -> bf16_t* { return (bf16_t*)(smem + 8192 + nb * 24576); };

    auto stage = [&](int kk, int nb) {
        bf16_t* dA = ldsA(nb);
        bf16_t* dB = ldsB(nb);
        #pragma unroll
        for (int cc = 0; cc < 2; ++cc) {
            const int r0  = wave * 16 + cc * 8;
            const int row = r0 + (lane >> 3);
            const int cs  = (lane & 7) ^ (row & 7);
            gl_lds16(A + (size_t)row * HID_ + kk + cs * 8, dA + r0 * 64);
        }
        #pragma unroll
        for (int cc = 0; cc < 4; ++cc) {
            const int r0  = wave * 32 + cc * 8;
            const int row = r0 + (lane >> 3);
            const int cs  = (lane & 7) ^ (row & 7);
            gl_lds16(W + (size_t)(n0 + row) * HID_ + kk + cs * 8, dB + r0 * 64);
        }
    };
    auto compute = [&](int nb) {
        const bf16_t* La = ldsA(nb);
        const bf16_t* Lb = ldsB(nb);
        #pragma unroll
        for (int h = 0; h < 2; ++h) {
            bf16x8 af[2], bfg[4];
            #pragma unroll
            for (int i = 0; i < 2; ++i) {
                const int r = wm + i * 16 + l16;
                const int c = (h * 4 + quad) ^ (r & 7);
                af[i] = *(const bf16x8*)&La[r * 64 + c * 8];
            }
            #pragma unroll
            for (int j = 0; j < 4; ++j) {
                const int r = wn + j * 16 + l16;
                const int c = (h * 4 + quad) ^ (r & 7);
                bfg[j] = *(const bf16x8*)&Lb[r * 64 + c * 8];
            }
            #pragma unroll
            for (int i = 0; i < 2; ++i)
                #pragma unroll
                for (int j = 0; j < 4; ++j)   // swapped operands -> D^T
                    acc[i][j] = __builtin_amdgcn_mfma_f32_16x16x32_bf16(bfg[j], af[i], acc[i][j], 0, 0, 0);
        }
    };

    stage(0, 0);
    __syncthreads();
    int buf = 0;
    for (int s = 0; s < 15; ++s) {
        stage((s + 1) * 64, buf ^ 1);   // prefetch in flight under compute
        compute(buf);
        __syncthreads();
        buf ^= 1;
    }
    compute(buf);

    // Store: m = m0+wm+i*16+l16; n = n0+wn+j*16+quad*4 (+reg). 16 B dwordx4/lane.
    #pragma unroll
    for (int i = 0; i < 2; ++i) {
        const int m = m0 + wm + i * 16 + l16;
        #pragma unroll
        for (int j = 0; j < 4; ++j) {
            const int nl = wn + j * 16 + quad * 4;
            const float4 b4 = *(const float4*)&bias[n0 + nl];
            float4 o;
            o.x = acc[i][j][0] + b4.x;
            o.y = acc[i][j][1] + b4.y;
            o.z = acc[i][j][2] + b4.z;
            o.w = acc[i][j][3] + b4.w;
            *(float4*)&Out[(size_t)(b * 256 + m) * OUT_ + n0 + nl] = o;
        }
    }
}

extern "C" void kernel_launch(void* const* d_in, const int* in_sizes, int n_in,
                              void* d_out, int out_size, void* d_ws, size_t ws_size,
                              hipStream_t stream) {
    const float* x         = (const float*)d_in[0];
    const int*   hetero    = (const int*)d_in[1];
    const float* fc1_table = (const float*)d_in[2];
    const float* fc2_table = (const float*)d_in[3];
    float*       out       = (float*)d_out;

    // Workspace layout (same budget as prior rounds):
    char* ws = (char*)d_ws;
    bf16_t* W1t = (bf16_t*)(ws);                         // 20x1024x512 bf16 = 20,971,520
    bf16_t* W2t = (bf16_t*)(ws + 20971520);              // 20x256x1024 bf16 = 10,485,760
    float*  b1  = (float*)(ws + 31457280);               // 20x1024 fp32
    float*  b2  = (float*)(ws + 31539200);               // 20x256 fp32
    bf16_t* H   = (bf16_t*)(ws + 31559680);              // 64x256x1024 bf16 = 33,554,432

    // 3 kernels (was 5): merged weight prep; fc1 reads X fp32 directly.
    cvt_weights<<<dim3(3840), 256, 0, stream>>>(fc1_table, fc2_table, W1t, W2t, b1, b2);
    fc1_gemm<<<dim3(1024), 256, 0, stream>>>(x, W1t, b1, hetero, H);
    fc2_gemm<<<dim3(512), 256, 0, stream>>>(H, W2t, b2, hetero, out);
}

// Round 5
// 178.545 us; speedup vs baseline: 1.0558x; 1.0002x over previous
//
#include <hip/hip_runtime.h>
#include <math.h>

// Problem constants
#define B_  64
#define T_  256
#define IN_ 512
#define HID_ 1024
#define OUT_ 256
#define NDOM 20

typedef __bf16 bf16_t;
typedef __bf16 bf16x8 __attribute__((ext_vector_type(8)));
typedef __bf16 bf16x4 __attribute__((ext_vector_type(4)));
typedef float  f32x4  __attribute__((ext_vector_type(4)));

// fp32 -> bf16 RNE, pure bit math
__device__ __forceinline__ unsigned f2bf_bits(float f) {
    unsigned u = __builtin_bit_cast(unsigned, f);
    return (u + 0x7FFFu + ((u >> 16) & 1u)) >> 16;
}
__device__ __forceinline__ unsigned pack_bf16x2(float x, float y) {
    return f2bf_bits(x) | (f2bf_bits(y) << 16);
}

// Async global->LDS, 16 B per lane. LDS dest = wave-uniform base + lane*16 (m104).
__device__ __forceinline__ void gl_lds16(const void* g, void* l) {
    __builtin_amdgcn_global_load_lds(
        (const __attribute__((address_space(1))) unsigned*)g,
        (__attribute__((address_space(3))) unsigned*)l,
        16, 0, 0);
}

// Branchless exact-gelu via Abramowitz-Stegun 7.1.26 erf (|err| <= 1.5e-7).
__device__ __forceinline__ float gelu_fast(float v) {
    const float t = v * 0.70710678118654752f;
    const float a = __builtin_fabsf(t);
    const float k = __builtin_amdgcn_rcpf(__builtin_fmaf(0.3275911f, a, 1.0f));
    float p = __builtin_fmaf(1.061405429f, k, -1.453152027f);
    p = __builtin_fmaf(p, k, 1.421413741f);
    p = __builtin_fmaf(p, k, -0.284496736f);
    p = __builtin_fmaf(p, k, 0.254829592f);
    p = p * k;
    const float e  = __expf(-a * a);
    const float er = __builtin_fmaf(-p, e, 1.0f);          // erf(|t|)
    const float erf_t = __builtin_copysignf(er, t);
    return 0.5f * v * (1.0f + erf_t);
}

// ---------------------------------------------------------------------------
// Merged prep: X fp32->bf16 copy-convert + both weight transposes, ONE launch.
// Blocks [0,2048):        X cvt, 4 float4/thread (grid-stride style, contiguous).
// Blocks [2048,4608):     fc1 W tiles (K=512,N=1024): 20 d x 8 k x 16 n.
// Blocks [4608,5888):     fc2 W tiles (K=1024,N=256): 20 d x 16 k x 4 n.
__global__ __launch_bounds__(256) void prep_all(
    const float* __restrict__ X,  bf16_t* __restrict__ Xbf,
    const float* __restrict__ T1, const float* __restrict__ T2,
    bf16_t* __restrict__ W1t, bf16_t* __restrict__ W2t,
    float* __restrict__ b1, float* __restrict__ b2)
{
    const int tid = threadIdx.x;
    int blk = blockIdx.x;

    if (blk < 2048) {                       // ---- X convert: 2048*1024 float4
        #pragma unroll
        for (int r = 0; r < 4; ++r) {
            const size_t idx = (size_t)blk * 1024 + r * 256 + tid;
            float4 v = ((const float4*)X)[idx];
            uint2 p;
            p.x = pack_bf16x2(v.x, v.y);
            p.y = pack_bf16x2(v.z, v.w);
            ((uint2*)Xbf)[idx] = p;
        }
        return;
    }

    // ---- weight transpose tile
    const float* table; bf16_t* Wt; float* Bias;
    int K, N, d, n0, k0;
    if (blk < 4608) {
        blk -= 2048;
        d = blk >> 7; const int rem = blk & 127;
        k0 = (rem >> 4) * 64; n0 = (rem & 15) * 64;
        K = 512; N = 1024; table = T1; Wt = W1t; Bias = b1;
    } else {
        blk -= 4608;
        d = blk >> 6; const int rem = blk & 63;
        k0 = (rem >> 2) * 64; n0 = (rem & 3) * 64;
        K = 1024; N = 256; table = T2; Wt = W2t; Bias = b2;
    }
    const float* W = table + (size_t)d * ((size_t)K * N + N);

    __shared__ float t[64][65];

    #pragma unroll
    for (int r = 0; r < 4; ++r) {
        const int kl = (tid >> 4) + r * 16;
        const int nl = (tid & 15) * 4;
        float4 v = *(const float4*)(W + (size_t)(k0 + kl) * N + n0 + nl);
        t[kl][nl + 0] = v.x; t[kl][nl + 1] = v.y;
        t[kl][nl + 2] = v.z; t[kl][nl + 3] = v.w;
    }
    __syncthreads();

    bf16_t* Wtd = Wt + (size_t)d * K * N;
    #pragma unroll
    for (int r = 0; r < 4; ++r) {
        const int nl = (tid >> 4) + r * 16;
        const int k4 = (tid & 15) * 4;
        uint2 p;
        p.x = pack_bf16x2(t[k4 + 0][nl], t[k4 + 1][nl]);
        p.y = pack_bf16x2(t[k4 + 2][nl], t[k4 + 3][nl]);
        *(uint2*)(Wtd + (size_t)(n0 + nl) * K + k0 + k4) = p;
    }

    if (k0 == 0 && tid < 64)
        Bias[(size_t)d * N + n0 + tid] = W[(size_t)K * N + n0 + tid];
}

// ---------------------------------------------------------------------------
// fc1: H[b] = gelu(Xbf[b] (256x512 bf16) @ W1t[d]^T + b1), H bf16.
// 128x128 tile, BK=32, double-buffered (32 KB GEMM LDS -> 4 blocks/CU),
// single barrier per K-step; both operands staged via gl_lds16 (bf16) —
// the twice-verified fastest staging path. Swizzle: LDS chunk q of row r
// holds global chunk q ^ ((r>>1)&3).
#define CT_STRIDE 136   // epilogue row stride (bf16): 128 data + 8 pad
__global__ __launch_bounds__(256) void fc1_gemm(
    const bf16_t* __restrict__ Xbf,   // B x 256 x 512 bf16
    const bf16_t* __restrict__ W1t,   // D x 1024 x 512 [n][k]
    const float*  __restrict__ Bias,  // D x 1024
    const int*    __restrict__ hetero,
    bf16_t*       __restrict__ H)     // B x 256 x 1024
{
    const int id   = blockIdx.x;          // 1024 blocks
    const int g    = id & 127;            // stride-128 ids share X-tile -> same XCD
    const int nidx = id >> 7;
    const int b    = g >> 1;
    const int m0   = (g & 1) * 128;
    const int n0   = nidx * 128;
    const int d    = hetero[2 * b];
    const bf16_t* W    = W1t + (size_t)d * HID_ * IN_;
    const float*  bias = Bias + (size_t)d * HID_;
    const bf16_t* A    = Xbf + (size_t)(b * 256 + m0) * IN_;

    __shared__ __attribute__((aligned(16))) char smem[34816];

    const int tid  = threadIdx.x;
    const int wave = tid >> 6;
    const int lane = tid & 63;
    const int l16  = lane & 15;
    const int quad = lane >> 4;
    const int wm   = (wave >> 1) * 64;
    const int wn   = (wave & 1) * 64;

    f32x4 acc[4][4] = {};

    auto ldsA = [&](int nb) -> bf16_t* { return (bf16_t*)(smem + nb * 16384); };
    auto ldsB = [&](int nb) -> bf16_t* { return (bf16_t*)(smem + 8192 + nb * 16384); };

    auto stageA = [&](int kk, bf16_t* dst) {
        #pragma unroll
        for (int cc = 0; cc < 2; ++cc) {
            const int r0  = wave * 32 + cc * 16;
            const int row = r0 + (lane >> 2);
            const int cs  = (lane & 3) ^ ((row >> 1) & 3);
            gl_lds16(A + (size_t)row * IN_ + kk + cs * 8, dst + r0 * 32);
        }
    };
    auto stageB = [&](int kk, bf16_t* dst) {
        #pragma unroll
        for (int cc = 0; cc < 2; ++cc) {
            const int r0  = wave * 32 + cc * 16;
            const int row = r0 + (lane >> 2);
            const int cs  = (lane & 3) ^ ((row >> 1) & 3);
            gl_lds16(W + (size_t)(n0 + row) * IN_ + kk + cs * 8, dst + r0 * 32);
        }
    };
    auto compute = [&](const bf16_t* La, const bf16_t* Lb) {
        bf16x8 af[4], bfg[4];
        #pragma unroll
        for (int i = 0; i < 4; ++i) {
            const int r = wm + i * 16 + l16;
            const int c = quad ^ ((r >> 1) & 3);
            af[i] = *(const bf16x8*)&La[r * 32 + c * 8];
        }
        #pragma unroll
        for (int j = 0; j < 4; ++j) {
            const int r = wn + j * 16 + l16;
            const int c = quad ^ ((r >> 1) & 3);
            bfg[j] = *(const bf16x8*)&Lb[r * 32 + c * 8];
        }
        #pragma unroll
        for (int i = 0; i < 4; ++i)
            #pragma unroll
            for (int j = 0; j < 4; ++j)   // swapped operands -> D^T
                acc[i][j] = __builtin_amdgcn_mfma_f32_16x16x32_bf16(bfg[j], af[i], acc[i][j], 0, 0, 0);
    };

    // Prologue
    stageA(0, ldsA(0));
    stageB(0, ldsB(0));
    __syncthreads();

    // 16 K-steps, single barrier each; prefetch in flight under compute.
    int buf = 0;
    for (int s = 0; s < 15; ++s) {
        stageA((s + 1) * 32, ldsA(buf ^ 1));
        stageB((s + 1) * 32, ldsB(buf ^ 1));
        compute(ldsA(buf), ldsB(buf));
        __syncthreads();
        buf ^= 1;
    }
    compute(ldsA(buf), ldsB(buf));
    __syncthreads();                          // before Ct alias

    bf16_t* Ct = (bf16_t*)smem;               // [128][CT_STRIDE] = 34816 B

    // Epilogue: D^T: m = wm+i*16+l16, n = wn+j*16+quad*4 (+reg).
    #pragma unroll
    for (int i = 0; i < 4; ++i) {
        const int m = wm + i * 16 + l16;
        #pragma unroll
        for (int j = 0; j < 4; ++j) {
            const int nl = wn + j * 16 + quad * 4;
            const float4 b4 = *(const float4*)&bias[n0 + nl];
            bf16x4 w;
            w[0] = (bf16_t)gelu_fast(acc[i][j][0] + b4.x);
            w[1] = (bf16_t)gelu_fast(acc[i][j][1] + b4.y);
            w[2] = (bf16_t)gelu_fast(acc[i][j][2] + b4.z);
            w[3] = (bf16_t)gelu_fast(acc[i][j][3] + b4.w);
            *(bf16x4*)&Ct[m * CT_STRIDE + nl] = w;
        }
    }
    __syncthreads();

    // Coalesced H store: 128 rows x 256 B.
    #pragma unroll
    for (int it = 0; it < 8; ++it) {
        const int row = it * 16 + (tid >> 4);
        const int ch  = tid & 15;
        uint4 v = *(const uint4*)&Ct[row * CT_STRIDE + ch * 8];
        *(uint4*)&H[((size_t)(b * 256 + m0 + row)) * HID_ + n0 + ch * 8] = v;
    }
}

// ---------------------------------------------------------------------------
// fc2: out[b] = H[b] (256x1024 bf16) @ W2t[d]^T + b2, fp32 out.
// 64(M)x128(N) tile, BK=64, double-buffered (48 KB), single barrier per step.
__global__ __launch_bounds__(256) void fc2_gemm(
    const bf16_t* __restrict__ H,
    const bf16_t* __restrict__ W2t,   // D x 256 x 1024 [n][k]
    const float*  __restrict__ Bias,  // D x 256
    const int*    __restrict__ hetero,
    float*        __restrict__ Out)   // B x 256 x 256
{
    const int id   = blockIdx.x;          // 512 blocks
    const int g    = id & 255;            // stride-256 ids share H-tile -> same XCD
    const int nidx = id >> 8;             // 0..1
    const int b    = g >> 2;
    const int m0   = (g & 3) * 64;
    const int n0   = nidx * 128;
    const int d    = hetero[2 * b];
    const bf16_t* W    = W2t + (size_t)d * OUT_ * HID_;
    const float*  bias = Bias + (size_t)d * OUT_;
    const bf16_t* A    = H + (size_t)(b * 256 + m0) * HID_;

    __shared__ __attribute__((aligned(16))) char smem[49152];   // 48 KB

    const int tid  = threadIdx.x;
    const int wave = tid >> 6;
    const int lane = tid & 63;
    const int l16  = lane & 15;
    const int quad = lane >> 4;
    const int wm   = (wave >> 1) * 32;
    const int wn   = (wave & 1) * 64;

    f32x4 acc[2][4] = {};

    auto ldsA = [&](int nb) -> bf16_t* { return (bf16_t*)(smem + nb * 24576); };
    auto ldsB = [&](int nb) -> bf16_t* { return (bf16_t*)(smem + 8192 + nb * 24576); };

    auto stage = [&](int kk, int nb) {
        bf16_t* dA = ldsA(nb);
        bf16_t* dB = ldsB(nb);
        #pragma unroll
        for (int cc = 0; cc < 2; ++cc) {
            const int r0  = wave * 16 + cc * 8;
            const int row = r0 + (lane >> 3);
            const int cs  = (lane & 7) ^ (row & 7);
            gl_lds16(A + (size_t)row * HID_ + kk + cs * 8, dA + r0 * 64);
        }
        #pragma unroll
        for (int cc = 0; cc < 4; ++cc) {
            const int r0  = wave * 32 + cc * 8;
            const int row = r0 + (lane >> 3);
            const int cs  = (lane & 7) ^ (row & 7);
            gl_lds16(W + (size_t)(n0 + row) * HID_ + kk + cs * 8, dB + r0 * 64);
        }
    };
    auto compute = [&](int nb) {
        const bf16_t* La = ldsA(nb);
        const bf16_t* Lb = ldsB(nb);
        #pragma unroll
        for (int h = 0; h < 2; ++h) {
            bf16x8 af[2], bfg[4];
            #pragma unroll
            for (int i = 0; i < 2; ++i) {
                const int r = wm + i * 16 + l16;
                const int c = (h * 4 + quad) ^ (r & 7);
                af[i] = *(const bf16x8*)&La[r * 64 + c * 8];
            }
            #pragma unroll
            for (int j = 0; j < 4; ++j) {
                const int r = wn + j * 16 + l16;
                const int c = (h * 4 + quad) ^ (r & 7);
                bfg[j] = *(const bf16x8*)&Lb[r * 64 + c * 8];
            }
            #pragma unroll
            for (int i = 0; i < 2; ++i)
                #pragma unroll
                for (int j = 0; j < 4; ++j)   // swapped operands -> D^T
                    acc[i][j] = __builtin_amdgcn_mfma_f32_16x16x32_bf16(bfg[j], af[i], acc[i][j], 0, 0, 0);
        }
    };

    stage(0, 0);
    __syncthreads();
    int buf = 0;
    for (int s = 0; s < 15; ++s) {
        stage((s + 1) * 64, buf ^ 1);   // prefetch in flight under compute
        compute(buf);
        __syncthreads();
        buf ^= 1;
    }
    compute(buf);

    // Store: m = m0+wm+i*16+l16; n = n0+wn+j*16+quad*4 (+reg). 16 B dwordx4/lane.
    #pragma unroll
    for (int i = 0; i < 2; ++i) {
        const int m = m0 + wm + i * 16 + l16;
        #pragma unroll
        for (int j = 0; j < 4; ++j) {
            const int nl = wn + j * 16 + quad * 4;
            const float4 b4 = *(const float4*)&bias[n0 + nl];
            float4 o;
            o.x = acc[i][j][0] + b4.x;
            o.y = acc[i][j][1] + b4.y;
            o.z = acc[i][j][2] + b4.z;
            o.w = acc[i][j][3] + b4.w;
            *(float4*)&Out[(size_t)(b * 256 + m) * OUT_ + n0 + nl] = o;
        }
    }
}

extern "C" void kernel_launch(void* const* d_in, const int* in_sizes, int n_in,
                              void* d_out, int out_size, void* d_ws, size_t ws_size,
                              hipStream_t stream) {
    const float* x         = (const float*)d_in[0];
    const int*   hetero    = (const int*)d_in[1];
    const float* fc1_table = (const float*)d_in[2];
    const float* fc2_table = (const float*)d_in[3];
    float*       out       = (float*)d_out;

    // Workspace layout (same budget as prior rounds):
    char* ws = (char*)d_ws;
    bf16_t* W1t = (bf16_t*)(ws);                         // 20x1024x512 bf16 = 20,971,520
    bf16_t* W2t = (bf16_t*)(ws + 20971520);              // 20x256x1024 bf16 = 10,485,760
    float*  b1  = (float*)(ws + 31457280);               // 20x1024 fp32
    float*  b2  = (float*)(ws + 31539200);               // 20x256 fp32
    bf16_t* H   = (bf16_t*)(ws + 31559680);              // 64x256x1024 bf16 = 33,554,432

    // Xbf lives in d_out (16,777,216 B = exactly out_size*4): fc1 reads it,
    // fc2 overwrites d_out afterwards (stream-ordered).
    bf16_t* Xbf = (bf16_t*)d_out;

    // 3 kernels: merged prep (X cvt + both weight transposes), fc1, fc2.
    prep_all<<<dim3(5888), 256, 0, stream>>>(x, Xbf, fc1_table, fc2_table,
                                             W1t, W2t, b1, b2);
    fc1_gemm<<<dim3(1024), 256, 0, stream>>>(Xbf, W1t, b1, hetero, H);
    fc2_gemm<<<dim3(512), 256, 0, stream>>>(H, W2t, b2, hetero, out);
}